// Round 17
// baseline (1034.391 us; speedup 1.0000x reference)
//
#include <hip/hip_runtime.h>
#include <hip/hip_bf16.h>

// B=2, S=4096, D=1024, H=16, HD=64, M=512, L=1024, HID=2816, 8 scan steps.
// R13 (1022us verified) -> R14: w2 GEMM split-K 2->4 (grid (16,16,4)=1024
// blocks = 4/CU, Ksplit=704); om2P expanded to 4 planes; rmsnorm sums np=4.
// Isolates the split-K=4 variable R7 bundled with the falsified attn rewrite.
// Everything else identical to R13.

#define D_    1024
#define H_    16
#define HD_   64
#define M_    512
#define L_    1024
#define HID_  2816
#define NSTEP 8

typedef __hip_bfloat16 bf16;
typedef _Float16 f16;
typedef __attribute__((ext_vector_type(8))) short short8;
typedef __attribute__((ext_vector_type(8))) _Float16 f16x8;
typedef __attribute__((ext_vector_type(4))) _Float16 f16x4;
typedef __attribute__((ext_vector_type(2))) _Float16 f16x2;
typedef __attribute__((ext_vector_type(4))) float floatx4;

// ---------------- dtype probe ----------------
__global__ void probe_dtype(const void* x, int* flag) {
  int lane = threadIdx.x;
  unsigned short v = ((const unsigned short*)x)[2 * lane];
  int e = (v >> 7) & 0xFF;
  bool sane = (e >= 100 && e <= 140);
  unsigned long long m = __ballot(sane);
  if (lane == 0) flag[0] = (__popcll(m) >= 40) ? 1 : 0;  // 1 = bf16 inputs
}

__device__ __forceinline__ float load_any(const void* p, long i, int isbf) {
  return isbf ? __bfloat162float(((const bf16*)p)[i]) : ((const float*)p)[i];
}

// ---------------- converts ----------------
// dest row = n*stride + off  (stride=2 interleaves w1/w3 columns)
__global__ __launch_bounds__(256) void transpose_cast(const void* in, bf16* out,
                                                      int K, int N, const int* flagp,
                                                      int stride, int off) {
  __shared__ float tile[32][33];
  int isbf = flagp[0];
  int tx = threadIdx.x & 31, ty = threadIdx.x >> 5;
  int n = blockIdx.x * 32 + tx;
#pragma unroll
  for (int i = 0; i < 4; i++) {
    int k = blockIdx.y * 32 + ty + i * 8;
    tile[ty + i * 8][tx] = load_any(in, (long)k * N + n, isbf);
  }
  __syncthreads();
  int k2 = blockIdx.y * 32 + tx;
#pragma unroll
  for (int i = 0; i < 4; i++) {
    int n2 = blockIdx.x * 32 + ty + i * 8;
    out[((long)n2 * stride + off) * K + k2] = __float2bfloat16(tile[tx][ty + i * 8]);
  }
}

// batched 1024x1024 transposes: z picks (src,dst) pair.
__global__ __launch_bounds__(256) void transpose_cast_d7(
    const void* wq, const void* wk, const void* wv, const void* wm,
    const void* wkm, const void* wvm, const void* wo,
    bf16* wqkvT, bf16* wmT, bf16* wkmvmT, bf16* woT, const int* flagp) {
  __shared__ float tile[32][33];
  int z = blockIdx.z;
  const void* in;
  bf16* out;
  switch (z) {
    case 0: in = wq;  out = wqkvT;               break;
    case 1: in = wk;  out = wqkvT + 1048576;     break;
    case 2: in = wv;  out = wqkvT + 2 * 1048576; break;
    case 3: in = wm;  out = wmT;                 break;
    case 4: in = wkm; out = wkmvmT;              break;
    case 5: in = wvm; out = wkmvmT + 1048576;    break;
    default: in = wo; out = woT;                 break;
  }
  int isbf = flagp[0];
  int tx = threadIdx.x & 31, ty = threadIdx.x >> 5;
  int n = blockIdx.x * 32 + tx;
#pragma unroll
  for (int i = 0; i < 4; i++) {
    int k = blockIdx.y * 32 + ty + i * 8;
    tile[ty + i * 8][tx] = load_any(in, (long)k * 1024 + n, isbf);
  }
  __syncthreads();
  int k2 = blockIdx.y * 32 + tx;
#pragma unroll
  for (int i = 0; i < 4; i++) {
    int n2 = blockIdx.x * 32 + ty + i * 8;
    out[(long)n2 * 1024 + k2] = __float2bfloat16(tile[tx][ty + i * 8]);
  }
}

__global__ __launch_bounds__(256) void cast_to_bf16(const void* in, bf16* out, int n,
                                                    const int* flagp) {
  int i = blockIdx.x * 256 + threadIdx.x;
  if (i < n) out[i] = __float2bfloat16(load_any(in, i, flagp[0]));
}

__global__ __launch_bounds__(256) void cast_to_f32(const void* in, float* out, int n,
                                                   const int* flagp) {
  int i = blockIdx.x * 256 + threadIdx.x;
  if (i < n) out[i] = load_any(in, i, flagp[0]);
}

__global__ __launch_bounds__(256) void init_om(const void* in, bf16* om, const int* flagp) {
  int i = blockIdx.x * 256 + threadIdx.x;  // 1048576
  int rem = i & (M_ * D_ - 1);
  om[i] = __float2bfloat16(load_any(in, rem, flagp[0]));
}

// ---------------- 64x64 MFMA GEMM core (shared macro body) ----------------
#define GEMM64_BODY(Aptr, WTptr, Kld, kbeg, kend)                                   \
  __shared__ char smem[16384];                                                      \
  char* aT = smem;                                                                  \
  char* bT = smem + 8192;                                                           \
  int tid = threadIdx.x;                                                            \
  int wave = tid >> 6, lane = tid & 63;                                             \
  int wm_ = wave >> 1, wn_ = wave & 1;                                              \
  floatx4 acc[2][2] = {};                                                           \
  int q0 = tid, q1 = tid + 256;                                                     \
  int am0 = q0 >> 3, ac0 = q0 & 7;                                                  \
  int am1 = q1 >> 3, ac1 = q1 & 7;                                                  \
  long grow0 = R0 + am0, grow1 = R0 + am1;                                          \
  long bn0 = (long)(C0 + am0) * (Kld), bn1 = (long)(C0 + am1) * (Kld);              \
  int lofa0 = (am0 * 8 + (ac0 ^ (am0 & 7))) * 16;                                   \
  int lofa1 = (am1 * 8 + (ac1 ^ (am1 & 7))) * 16;                                   \
  for (int k0 = (kbeg); k0 < (kend); k0 += 64) {                                    \
    uint4 va0 = *(const uint4*)((Aptr) + grow0 * (Kld) + k0 + ac0 * 8);             \
    uint4 va1 = *(const uint4*)((Aptr) + grow1 * (Kld) + k0 + ac1 * 8);             \
    uint4 vb0 = *(const uint4*)((WTptr) + bn0 + k0 + ac0 * 8);                      \
    uint4 vb1 = *(const uint4*)((WTptr) + bn1 + k0 + ac1 * 8);                      \
    __syncthreads();                                                                \
    *(uint4*)(aT + lofa0) = va0;                                                    \
    *(uint4*)(aT + lofa1) = va1;                                                    \
    *(uint4*)(bT + lofa0) = vb0;                                                    \
    *(uint4*)(bT + lofa1) = vb1;                                                    \
    __syncthreads();                                                                \
    _Pragma("unroll") for (int kki = 0; kki < 2; ++kki) {                           \
      int cbase = kki * 4 + (lane >> 4);                                            \
      short8 af[2], bfr[2];                                                         \
      _Pragma("unroll") for (int i = 0; i < 2; ++i) {                               \
        int ml = wm_ * 32 + i * 16 + (lane & 15);                                   \
        af[i] = *(const short8*)(aT + (ml * 8 + (cbase ^ (ml & 7))) * 16);          \
        int nl = wn_ * 32 + i * 16 + (lane & 15);                                   \
        bfr[i] = *(const short8*)(bT + (nl * 8 + (cbase ^ (nl & 7))) * 16);         \
      }                                                                             \
      _Pragma("unroll") for (int i = 0; i < 2; ++i)                                 \
          _Pragma("unroll") for (int j = 0; j < 2; ++j) acc[i][j] =                 \
              __builtin_amdgcn_mfma_f32_16x16x32_bf16(af[i], bfr[j], acc[i][j],     \
                                                      0, 0, 0);                     \
    }                                                                               \
  }

// split-K via blockIdx.z: plane z -> outP + z*2^20 (all uses are 1024x1024 out).
__global__ __launch_bounds__(256) void gemm64_sk(
    const bf16* __restrict__ A, const bf16* __restrict__ WT,
    float* __restrict__ outP, int N, int Kfull, int Ksplit) {
  int C0 = blockIdx.x * 64, R0 = blockIdx.y * 64;
  int kb = blockIdx.z;
  float* out = outP + ((size_t)kb << 20);
  int kbeg = kb * Ksplit;
  GEMM64_BODY(A, WT, Kfull, kbeg, kbeg + Ksplit)
#pragma unroll
  for (int i = 0; i < 2; ++i)
#pragma unroll
    for (int j = 0; j < 2; ++j) {
      int row = R0 + wm_ * 32 + i * 16 + (lane >> 4) * 4;
      int col = C0 + wn_ * 32 + j * 16 + (lane & 15);
#pragma unroll
      for (int rg = 0; rg < 4; ++rg)
        out[(long)(row + rg) * N + col] = acc[i][j][rg];
    }
}

// kmvm GEMM (om2 @ [wkm|wvm], N=2048, K=1024) with fused rope (K side) and
// transpose (V side). Rows = b*512+pos; cols 0..1023 -> k_mem, 1024.. -> v_memT.
__global__ __launch_bounds__(256) void gemm64_kmvm(
    const bf16* __restrict__ A, const bf16* __restrict__ WT,
    const float* __restrict__ cosf, const float* __restrict__ sinf,
    f16* __restrict__ k_mem, f16* __restrict__ v_memT) {
  int C0 = blockIdx.x * 64, R0 = blockIdx.y * 64;
  GEMM64_BODY(A, WT, 1024, 0, 1024)
#pragma unroll
  for (int i = 0; i < 2; ++i)
#pragma unroll
    for (int j = 0; j < 2; ++j) {
      int row0 = R0 + wm_ * 32 + i * 16 + (lane >> 4) * 4;
      int col = C0 + wn_ * 32 + j * 16 + (lane & 15);
#pragma unroll
      for (int rg = 0; rg < 4; ++rg) {
        float v = acc[i][j][rg];
        int row = row0 + rg;
        int b = row >> 9, pos = row & 511;
        if (C0 < 1024) {
          // K side: rope pair (2i,2i+1) sits in adjacent lanes
          float partner = __shfl_xor(v, 1);
          int ii = (col & 63) >> 1;
          float c = cosf[pos * 32 + ii], s = sinf[pos * 32 + ii];
          float o = (col & 1) ? (partner * s + v * c) : (v * c - partner * s);
          int bh = b * 16 + ((col >> 6) & 15);
          k_mem[((size_t)bh * 512 + pos) * 64 + (col & 63)] = (f16)o;
        } else {
          int d = col & 63;
          int bh = b * 16 + ((col - 1024) >> 6);
          v_memT[((size_t)bh * 64 + d) * 512 + pos] = (f16)v;
        }
      }
    }
}

// ---------------- 128x128 MFMA GEMM, global_load_lds (m97 structure) --------
// out_mode: 1 = f16, 2 = per flag, 4 = fused qkv rope/transpose.
__global__ __launch_bounds__(256) void gemm128(
    const bf16* __restrict__ A, const bf16* __restrict__ WT,
    void* __restrict__ out, const int* __restrict__ flagp,
    int N, int K, int out_mode,
    const float* __restrict__ cosf, const float* __restrict__ sinf,
    f16* __restrict__ q_x, f16* __restrict__ k_x, f16* __restrict__ v_xT) {
  __shared__ char smem[32768];  // A 16K | B 16K
  int tid = threadIdx.x;
  int w = tid >> 6, lane = tid & 63;
  int C0 = blockIdx.x * 128, R0 = blockIdx.y * 128;
  int wm = (w >> 1) * 64, wn = (w & 1) * 64;
  int g = lane >> 4, n16 = lane & 15;
  floatx4 acc[4][4] = {};
  int lr = lane >> 3, lc = lane & 7;

  for (int k0 = 0; k0 < K; k0 += 64) {
    __syncthreads();
#pragma unroll
    for (int i = 0; i < 4; ++i) {
      int m = w * 32 + i * 8 + lr;
      int cg = lc ^ (m & 7);
      const bf16* ga = A + (size_t)(R0 + m) * K + k0 + cg * 8;
      const bf16* gb = WT + (size_t)(C0 + m) * K + k0 + cg * 8;
      __builtin_amdgcn_global_load_lds(
          (const __attribute__((address_space(1))) void*)ga,
          (__attribute__((address_space(3))) void*)(smem + (w * 32 + i * 8) * 128),
          16, 0, 0);
      __builtin_amdgcn_global_load_lds(
          (const __attribute__((address_space(1))) void*)gb,
          (__attribute__((address_space(3))) void*)(smem + 16384 + (w * 32 + i * 8) * 128),
          16, 0, 0);
    }
    __syncthreads();
#pragma unroll
    for (int kk = 0; kk < 2; ++kk) {
      short8 af[4], bfr[4];
#pragma unroll
      for (int i = 0; i < 4; ++i) {
        int ml = wm + i * 16 + n16;
        af[i] = *(const short8*)(smem + (ml * 8 + ((kk * 4 + g) ^ (ml & 7))) * 16);
        int nl = wn + i * 16 + n16;
        bfr[i] = *(const short8*)(smem + 16384 + (nl * 8 + ((kk * 4 + g) ^ (nl & 7))) * 16);
      }
#pragma unroll
      for (int i = 0; i < 4; ++i)
#pragma unroll
        for (int j = 0; j < 4; ++j)
          acc[i][j] = __builtin_amdgcn_mfma_f32_16x16x32_bf16(af[i], bfr[j], acc[i][j], 0, 0, 0);
    }
  }
  int isbf = flagp ? flagp[0] : 0;
#pragma unroll
  for (int i = 0; i < 4; ++i)
#pragma unroll
    for (int j = 0; j < 4; ++j) {
      int row = R0 + wm + i * 16 + g * 4;
      int col = C0 + wn + j * 16 + n16;
      if (out_mode == 4) {
        // rows: b*4096 + t*512 + m; cols: [0,1024)=q, [1024,2048)=k, rest=v
        if (col < 2048) {
#pragma unroll
          for (int rg = 0; rg < 4; ++rg) {
            float v = acc[i][j][rg];
            float partner = __shfl_xor(v, 1);
            int r = row + rg;
            int m = r & 511, t = (r >> 9) & 7, b = r >> 12;
            int pos = 512 + m;
            int ii = (col & 63) >> 1;
            float c = cosf[pos * 32 + ii], s = sinf[pos * 32 + ii];
            float o = (col & 1) ? (partner * s + v * c) : (v * c - partner * s);
            int h = (col >> 6) & 15;
            size_t slab = (size_t)t * 32 + b * 16 + h;
            if (col < 1024)
              q_x[(slab * 512 + m) * 64 + (col & 63)] = (f16)(o * 0.125f);
            else
              k_x[(slab * 512 + m) * 64 + (col & 63)] = (f16)o;
          }
        } else {
          int r = row;
          int m = r & 511, t = (r >> 9) & 7, b = r >> 12;
          int d = col & 63, h = (col - 2048) >> 6;
          size_t slab = (size_t)t * 32 + b * 16 + h;
          f16x4 vv;
#pragma unroll
          for (int rg = 0; rg < 4; ++rg) vv[rg] = (f16)acc[i][j][rg];
          *(f16x4*)(v_xT + (slab * 64 + d) * 512 + m) = vv;
        }
        continue;
      }
#pragma unroll
      for (int rg = 0; rg < 4; ++rg) {
        float v = acc[i][j][rg];
        long off = (long)(row + rg) * N + col;
        if (out_mode == 1) ((f16*)out)[off] = (f16)v;
        else {
          if (isbf) ((bf16*)out)[off] = __float2bfloat16(v);
          else ((float*)out)[off] = v;
        }
      }
    }
}

// ---------------- 64x128 MFMA GEMM with fused silu-mul (w13 only) ----------
// BM=64 rows, BN=128 interleaved cols -> grid (44,16) = 704 blocks (2.75/CU).
// Same m97 staging/swizzle formulas; LDS 24KB (A 8K | B 16K).
__global__ __launch_bounds__(256) void gemm64x128_silu(
    const bf16* __restrict__ A, const bf16* __restrict__ WT,
    bf16* __restrict__ out, int K) {
  __shared__ char smem[24576];  // A 8K | B 16K
  int tid = threadIdx.x;
  int w = tid >> 6, lane = tid & 63;
  int C0 = blockIdx.x * 128, R0 = blockIdx.y * 64;
  int wm = (w >> 1) * 32, wn = (w & 1) * 64;
  int g = lane >> 4, n16 = lane & 15;
  floatx4 acc[2][4] = {};
  int lr = lane >> 3, lc = lane & 7;

  for (int k0 = 0; k0 < K; k0 += 64) {
    __syncthreads();
    // A tile: 64 rows; wave w stages rows w*16 .. w*16+15 (2 issues of 8 rows)
#pragma unroll
    for (int i = 0; i < 2; ++i) {
      int m = w * 16 + i * 8 + lr;
      int cg = lc ^ (m & 7);
      const bf16* ga = A + (size_t)(R0 + m) * K + k0 + cg * 8;
      __builtin_amdgcn_global_load_lds(
          (const __attribute__((address_space(1))) void*)ga,
          (__attribute__((address_space(3))) void*)(smem + (w * 16 + i * 8) * 128),
          16, 0, 0);
    }
    // B tile: 128 rows; wave w stages rows w*32 .. w*32+31 (4 issues)
#pragma unroll
    for (int i = 0; i < 4; ++i) {
      int m = w * 32 + i * 8 + lr;
      int cg = lc ^ (m & 7);
      const bf16* gb = WT + (size_t)(C0 + m) * K + k0 + cg * 8;
      __builtin_amdgcn_global_load_lds(
          (const __attribute__((address_space(1))) void*)gb,
          (__attribute__((address_space(3))) void*)(smem + 8192 + (w * 32 + i * 8) * 128),
          16, 0, 0);
    }
    __syncthreads();
#pragma unroll
    for (int kk = 0; kk < 2; ++kk) {
      short8 af[2], bfr[4];
#pragma unroll
      for (int i = 0; i < 2; ++i) {
        int ml = wm + i * 16 + n16;
        af[i] = *(const short8*)(smem + (ml * 8 + ((kk * 4 + g) ^ (ml & 7))) * 16);
      }
#pragma unroll
      for (int j = 0; j < 4; ++j) {
        int nl = wn + j * 16 + n16;
        bfr[j] = *(const short8*)(smem + 8192 + (nl * 8 + ((kk * 4 + g) ^ (nl & 7))) * 16);
      }
#pragma unroll
      for (int i = 0; i < 2; ++i)
#pragma unroll
        for (int j = 0; j < 4; ++j)
          acc[i][j] = __builtin_amdgcn_mfma_f32_16x16x32_bf16(af[i], bfr[j], acc[i][j], 0, 0, 0);
    }
  }
  // fused silu-mul epilogue: (g1,g3) pair sits in adjacent lanes (even/odd n16)
#pragma unroll
  for (int i = 0; i < 2; ++i)
#pragma unroll
    for (int j = 0; j < 4; ++j) {
      int row = R0 + wm + i * 16 + g * 4;
      int col = C0 + wn + j * 16 + n16;
#pragma unroll
      for (int rg = 0; rg < 4; ++rg) {
        float v = acc[i][j][rg];
        float partner = __shfl_xor(v, 1);
        if ((n16 & 1) == 0) {
          float a = v;
          float s = a / (1.f + __expf(-a));
          out[(long)(row + rg) * HID_ + (col >> 1)] = __float2bfloat16(s * partner);
        }
      }
    }
}

// ---------------- elementwise ----------------
// v = (X?X:0) + sum_{k<np} P[k<<20 + .]; Y = rmsnorm(v, Wn); sumout? = v.
__global__ __launch_bounds__(256) void rmsnorm_cast(const float* __restrict__ X,
                                                    const float* __restrict__ Wn,
                                                    bf16* __restrict__ Y,
                                                    const float* __restrict__ P,
                                                    int np,
                                                    float* __restrict__ sumout) {
  int row = blockIdx.x, tid = threadIdx.x;
  float vals[4], ss = 0.f;
#pragma unroll
  for (int i = 0; i < 4; i++) {
    int c = tid + i * 256;
    long idx = (long)row * D_ + c;
    float v = X ? X[idx] : 0.f;
    for (int k = 0; k < np; ++k) v += P[((size_t)k << 20) + idx];
    vals[i] = v;
    ss += v * v;
  }
#pragma unroll
  for (int off = 32; off; off >>= 1) ss += __shfl_xor(ss, off);
  __shared__ float wsum[4];
  int wv = tid >> 6, lane = tid & 63;
  if (lane == 0) wsum[wv] = ss;
  __syncthreads();
  ss = wsum[0] + wsum[1] + wsum[2] + wsum[3];
  float r = rsqrtf(ss * (1.0f / D_) + 1e-5f);
#pragma unroll
  for (int i = 0; i < 4; i++) {
    int c = tid + i * 256;
    if (sumout) sumout[(long)row * D_ + c] = vals[i];
    Y[(long)row * D_ + c] = __float2bfloat16(vals[i] * r * Wn[c]);
  }
}

// ---------------- fp16 MFMA flash attention ----------------
// attn_x: x-side causal half for ALL steps (scan-invariant), hoisted upfront.
// grid (8 qt, 32 bh, 8 t). Writes unnormalized partials + (m,l) per t.
__global__ __launch_bounds__(256) void attn_x(
    const f16* __restrict__ q_x, const f16* __restrict__ k_x,
    const f16* __restrict__ v_xT, float* __restrict__ OpartX,
    float* __restrict__ mpartX, float* __restrict__ lpartX) {
  __shared__ char smem[40960];  // K dbuf 2x8K | V^T dbuf 2x8K | P 4x2K
  int qt = blockIdx.x, bh = blockIdx.y, t = blockIdx.z;
  int tid = threadIdx.x;
  int w = tid >> 6, lane = tid & 63;
  int g = lane >> 4, n16 = lane & 15;
  int numc = qt + 1;
  int pos = 512 + qt * 64 + w * 16 + n16;
  size_t slab = (size_t)t * 32 + bh;

  f16x8 qf[2];
  {
    const f16* qp = q_x + (slab * 512 + qt * 64 + w * 16 + n16) * 64 + g * 8;
    qf[0] = *(const f16x8*)(qp);
    qf[1] = *(const f16x8*)(qp + 32);
  }
  floatx4 O[4] = {};
  float mrun = -1e30f, lrun = 0.f;

  int id0 = tid, id1 = tid + 256;
  int r0 = id0 >> 3, cc0 = id0 & 7;
  int r1 = id1 >> 3, cc1 = id1 & 7;
  int lof0 = ((r0 << 3) | (cc0 ^ (r0 & 7))) * 16;
  int lof1 = ((r1 << 3) | (cc1 ^ (r1 & 7))) * 16;

  uint4 kv0 = *(const uint4*)(k_x + (slab * 512 + r0) * 64 + cc0 * 8);
  uint4 kv1 = *(const uint4*)(k_x + (slab * 512 + r1) * 64 + cc1 * 8);
  uint4 vv0 = *(const uint4*)(v_xT + (slab * 64 + r0) * 512 + cc0 * 8);
  uint4 vv1 = *(const uint4*)(v_xT + (slab * 64 + r1) * 512 + cc1 * 8);

  char* Pw = smem + 32768 + w * 2048;

  for (int c = 0; c < numc; ++c) {
    char* Kb = smem + (c & 1) * 8192;
    char* Vb = smem + 16384 + (c & 1) * 8192;
    *(uint4*)(Kb + lof0) = kv0;
    *(uint4*)(Kb + lof1) = kv1;
    *(uint4*)(Vb + lof0) = vv0;
    *(uint4*)(Vb + lof1) = vv1;
    if (c + 1 < numc) {
      int ca = c + 1;
      kv0 = *(const uint4*)(k_x + (slab * 512 + ca * 64 + r0) * 64 + cc0 * 8);
      kv1 = *(const uint4*)(k_x + (slab * 512 + ca * 64 + r1) * 64 + cc1 * 8);
      vv0 = *(const uint4*)(v_xT + (slab * 64 + r0) * 512 + ca * 64 + cc0 * 8);
      vv1 = *(const uint4*)(v_xT + (slab * 64 + r1) * 512 + ca * 64 + cc1 * 8);
    }
    __syncthreads();

    floatx4 S[4] = {};
    __builtin_amdgcn_s_setprio(1);
#pragma unroll
    for (int kk = 0; kk < 2; ++kk) {
#pragma unroll
      for (int tn = 0; tn < 4; ++tn) {
        int row = tn * 16 + n16;
        f16x8 kf = *(const f16x8*)(Kb + (((row << 3) | ((kk * 4 + g) ^ (row & 7))) * 16));
        S[tn] = __builtin_amdgcn_mfma_f32_16x16x32_f16(kf, qf[kk], S[tn], 0, 0, 0);
      }
    }
    __builtin_amdgcn_s_setprio(0);
    if (c == numc - 1) {
      int kb = 512 + qt * 64;
#pragma unroll
      for (int tn = 0; tn < 4; ++tn)
#pragma unroll
        for (int r = 0; r < 4; ++r) {
          int key = kb + tn * 16 + g * 4 + r;
          if (key > pos) S[tn][r] = -1e30f;
        }
    }
    float smax = -1e30f;
#pragma unroll
    for (int tn = 0; tn < 4; ++tn)
#pragma unroll
      for (int r = 0; r < 4; ++r) smax = fmaxf(smax, S[tn][r]);
    smax = fmaxf(smax, __shfl_xor(smax, 16));
    smax = fmaxf(smax, __shfl_xor(smax, 32));
    float corr = 1.f;
    if (__any(smax > mrun + 8.f)) {
      float newm = fmaxf(mrun, smax);
      corr = __expf(mrun - newm);
      mrun = newm;
      float cr[4];
#pragma unroll
      for (int r = 0; r < 4; ++r) cr[r] = __shfl(corr, g * 4 + r);
#pragma unroll
      for (int dt = 0; dt < 4; ++dt)
#pragma unroll
        for (int r = 0; r < 4; ++r) O[dt][r] *= cr[r];
    }
    float lsum = 0.f;
#pragma unroll
    for (int tn = 0; tn < 4; ++tn) {
      f16x4 pk;
#pragma unroll
      for (int r = 0; r < 4; ++r) {
        float p = __expf(S[tn][r] - mrun);
        lsum += p;
        pk[r] = (f16)p;
      }
      int kapb = tn * 16 + g * 4;
      *(f16x4*)(Pw + (((n16 << 3) | ((kapb >> 3) ^ (n16 & 7))) * 16 + (kapb & 7) * 2)) = pk;
    }
    lsum += __shfl_xor(lsum, 16);
    lsum += __shfl_xor(lsum, 32);
    lrun = lrun * corr + lsum;
    __builtin_amdgcn_s_setprio(1);
#pragma unroll
    for (int kk = 0; kk < 2; ++kk) {
      f16x8 pf = *(const f16x8*)(Pw + (((n16 << 3) | ((kk * 4 + g) ^ (n16 & 7))) * 16));
#pragma unroll
      for (int dt = 0; dt < 4; ++dt) {
        int row = dt * 16 + n16;
        f16x8 vf =
            *(const f16x8*)(Vb + (((row << 3) | ((kk * 4 + g) ^ (row & 7))) * 16));
        O[dt] = __builtin_amdgcn_mfma_f32_16x16x32_f16(pf, vf, O[dt], 0, 0, 0);
      }
    }
    __builtin_amdgcn_s_setprio(0);
    __syncthreads();
  }
  int b = bh >> 4, h = bh & 15;
  if (g == 0) {
    int qq = qt * 64 + w * 16 + n16;
    mpartX[(size_t)t * 16384 + bh * 512 + qq] = mrun;
    lpartX[(size_t)t * 16384 + bh * 512 + qq] = lrun;
  }
#pragma unroll
  for (int dt = 0; dt < 4; ++dt)
#pragma unroll
    for (int r = 0; r < 4; ++r) {
      int qq = qt * 64 + w * 16 + g * 4 + r;
      size_t col = (size_t)h * 64 + dt * 16 + n16;
      OpartX[((size_t)t << 20) + (size_t)(b * 512 + qq) * 1024 + col] = O[dt][r];
    }
}

// attn_mem: memory half (8 chunks, no mask) + fused merge with x partials.
// grid (8 qt, 32 bh). Writes om_bf + outs_bf directly.
__global__ __launch_bounds__(256) void attn_mem(
    const f16* __restrict__ q_x, const f16* __restrict__ k_mem,
    const f16* __restrict__ v_memT, const float* __restrict__ OX,
    const float* __restrict__ mX, const float* __restrict__ lX,
    bf16* __restrict__ om_bf, bf16* __restrict__ outs_bf, int t) {
  __shared__ char smem[40960];  // K dbuf 2x8K | V^T dbuf 2x8K | P 4x2K
  int qt = blockIdx.x, bh = blockIdx.y;
  int tid = threadIdx.x;
  int w = tid >> 6, lane = tid & 63;
  int g = lane >> 4, n16 = lane & 15;
  size_t slab = (size_t)t * 32 + bh;

  f16x8 qf[2];
  {
    const f16* qp = q_x + (slab * 512 + qt * 64 + w * 16 + n16) * 64 + g * 8;
    qf[0] = *(const f16x8*)(qp);
    qf[1] = *(const f16x8*)(qp + 32);
  }
  floatx4 O[4] = {};
  float mrun = -1e30f, lrun = 0.f;

  int id0 = tid, id1 = tid + 256;
  int r0 = id0 >> 3, cc0 = id0 & 7;
  int r1 = id1 >> 3, cc1 = id1 & 7;
  int lof0 = ((r0 << 3) | (cc0 ^ (r0 & 7))) * 16;
  int lof1 = ((r1 << 3) | (cc1 ^ (r1 & 7))) * 16;

  uint4 kv0 = *(const uint4*)(k_mem + ((size_t)bh * 512 + r0) * 64 + cc0 * 8);
  uint4 kv1 = *(const uint4*)(k_mem + ((size_t)bh * 512 + r1) * 64 + cc1 * 8);
  uint4 vv0 = *(const uint4*)(v_memT + ((size_t)bh * 64 + r0) * 512 + cc0 * 8);
  uint4 vv1 = *(const uint4*)(v_memT + ((size_t)bh * 64 + r1) * 512 + cc1 * 8);

  char* Pw = smem + 32768 + w * 2048;

  for (int c = 0; c < 8; ++c) {
    char* Kb = smem + (c & 1) * 8192;
    char* Vb = smem + 16384 + (c & 1) * 8192;
    *(uint4*)(Kb + lof0) = kv0;
    *(uint4*)(Kb + lof1) = kv1;
    *(uint4*)(Vb + lof0) = vv0;
    *(uint4*)(Vb + lof1) = vv1;
    if (c + 1 < 8) {
      int ca = c + 1;
      kv0 = *(const uint4*)(k_mem + ((size_t)bh * 512 + ca * 64 + r0) * 64 + cc0 * 8);
      kv1 = *(const uint4*)(k_mem + ((size_t)bh * 512 + ca * 64 + r1) * 64 + cc1 * 8);
      vv0 = *(const uint4*)(v_memT + ((size_t)bh * 64 + r0) * 512 + ca * 64 + cc0 * 8);
      vv1 = *(const uint4*)(v_memT + ((size_t)bh * 64 + r1) * 512 + ca * 64 + cc1 * 8);
    }
    __syncthreads();

    floatx4 S[4] = {};
    __builtin_amdgcn_s_setprio(1);
#pragma unroll
    for (int kk = 0; kk < 2; ++kk) {
#pragma unroll
      for (int tn = 0; tn < 4; ++tn) {
        int row = tn * 16 + n16;
        f16x8 kf = *(const f16x8*)(Kb + (((row << 3) | ((kk * 4 + g) ^ (row & 7))) * 16));
        S[tn] = __builtin_amdgcn_mfma_f32_16x16x32_f16(kf, qf[kk], S[tn], 0, 0, 0);
      }
    }
    __builtin_amdgcn_s_setprio(0);
    float smax = -1e30f;
#pragma unroll
    for (int tn = 0; tn < 4; ++tn)
#pragma unroll
      for (int r = 0; r < 4; ++r) smax = fmaxf(smax, S[tn][r]);
    smax = fmaxf(smax, __shfl_xor(smax, 16));
    smax = fmaxf(smax, __shfl_xor(smax, 32));
    float corr = 1.f;
    if (__any(smax > mrun + 8.f)) {
      float newm = fmaxf(mrun, smax);
      corr = __expf(mrun - newm);
      mrun = newm;
      float cr[4];
#pragma unroll
      for (int r = 0; r < 4; ++r) cr[r] = __shfl(corr, g * 4 + r);
#pragma unroll
      for (int dt = 0; dt < 4; ++dt)
#pragma unroll
        for (int r = 0; r < 4; ++r) O[dt][r] *= cr[r];
    }
    float lsum = 0.f;
#pragma unroll
    for (int tn = 0; tn < 4; ++tn) {
      f16x4 pk;
#pragma unroll
      for (int r = 0; r < 4; ++r) {
        float p = __expf(S[tn][r] - mrun);
        lsum += p;
        pk[r] = (f16)p;
      }
      int kapb = tn * 16 + g * 4;
      *(f16x4*)(Pw + (((n16 << 3) | ((kapb >> 3) ^ (n16 & 7))) * 16 + (kapb & 7) * 2)) = pk;
    }
    lsum += __shfl_xor(lsum, 16);
    lsum += __shfl_xor(lsum, 32);
    lrun = lrun * corr + lsum;
    __builtin_amdgcn_s_setprio(1);
#pragma unroll
    for (int kk = 0; kk < 2; ++kk) {
      f16x8 pf = *(const f16x8*)(Pw + (((n16 << 3) | ((kk * 4 + g) ^ (n16 & 7))) * 16));
#pragma unroll
      for (int dt = 0; dt < 4; ++dt) {
        int row = dt * 16 + n16;
        f16x8 vf =
            *(const f16x8*)(Vb + (((row << 3) | ((kk * 4 + g) ^ (row & 7))) * 16));
        O[dt] = __builtin_amdgcn_mfma_f32_16x16x32_f16(pf, vf, O[dt], 0, 0, 0);
      }
    }
    __builtin_amdgcn_s_setprio(0);
    __syncthreads();
  }
  // fused merge with x-side partials
  int b = bh >> 4, h = bh & 15;
  float a1[4], a2[4], rden[4];
  int qqr[4];
#pragma unroll
  for (int r = 0; r < 4; ++r) {
    float m1 = __shfl(mrun, g * 4 + r);
    float l1 = __shfl(lrun, g * 4 + r);
    qqr[r] = qt * 64 + w * 16 + g * 4 + r;
    int idx = bh * 512 + qqr[r];
    float m2 = mX[idx], l2 = lX[idx];
    float Mx = fmaxf(m1, m2);
    a1[r] = __expf(m1 - Mx);
    a2[r] = __expf(m2 - Mx);
    rden[r] = 1.f / (a1[r] * l1 + a2[r] * l2);
  }
#pragma unroll
  for (int dt = 0; dt < 4; ++dt)
#pragma unroll
    for (int r = 0; r < 4; ++r) {
      size_t col = (size_t)h * 64 + dt * 16 + n16;
      size_t rowoff = (size_t)(b * 512 + qqr[r]) * 1024 + col;
      float o2 = OX[rowoff];
      float v = (a1[r] * O[dt][r] + a2[r] * o2) * rden[r];
      bf16 bv = __float2bfloat16(v);
      om_bf[rowoff] = bv;
      outs_bf[((size_t)(b * 4096 + t * 512 + qqr[r])) * 1024 + col] = bv;
    }
}

// ---------------- launch ----------------
extern "C" void kernel_launch(void* const* d_in, const int* in_sizes, int n_in,
                              void* d_out, int out_size, void* d_ws, size_t ws_size,
                              hipStream_t stream) {
  (void)in_sizes; (void)n_in; (void)out_size; (void)ws_size;
  const void* x   = d_in[0];
  const void* fc  = d_in[1];
  const void* fs  = d_in[2];
  const void* wq  = d_in[3];
  const void* wk  = d_in[4];
  const void* wv  = d_in[5];
  const void* wo  = d_in[6];
  const void* wm  = d_in[7];
  const void* wkm = d_in[8];
  const void* wvm = d_in[9];
  const void* w1  = d_in[10];
  const void* w3  = d_in[11];
  const void* w2  = d_in[12];
  const void* fnw = d_in[13];
  const void* mnw = d_in[14];
  const void* om0 = d_in[15];

  char* p = (char*)d_ws;
  auto alloc = [&](size_t bytes) -> char* {
    char* r = p;
    p += (bytes + 255) & ~(size_t)255;
    return r;
  };
  int*   flag    = (int*)alloc(256);
  bf16*  wqkvT   = (bf16*)alloc((size_t)3 * 1048576 * 2);
  bf16*  wmT     = (bf16*)alloc((size_t)1048576 * 2);
  bf16*  wkmvmT  = (bf16*)alloc((size_t)2 * 1048576 * 2);
  bf16*  w13T    = (bf16*)alloc((size_t)2 * 2883584 * 2);  // interleaved w1/w3
  bf16*  w2T     = (bf16*)alloc((size_t)2883584 * 2);
  bf16*  woT     = (bf16*)alloc((size_t)1048576 * 2);
  bf16*  xb      = (bf16*)alloc((size_t)8388608 * 2);
  float* cosf    = (float*)alloc((size_t)32768 * 4);
  float* sinf    = (float*)alloc((size_t)32768 * 4);
  float* ffnw    = (float*)alloc((size_t)1024 * 4);
  float* memw    = (float*)alloc((size_t)1024 * 4);
  bf16*  om_bf   = (bf16*)alloc((size_t)1048576 * 2);
  bf16*  outs_bf = (bf16*)alloc((size_t)8388608 * 2);
  f16*   q_x     = (f16*)alloc((size_t)8 * 32 * 512 * 64 * 2);
  f16*   k_x     = (f16*)alloc((size_t)8 * 32 * 512 * 64 * 2);
  f16*   v_xT    = (f16*)alloc((size_t)8 * 32 * 512 * 64 * 2);
  float* OpartX  = (float*)alloc((size_t)8 * 1048576 * 4);  // 32 MB x-partials
  float* mpartX  = (float*)alloc((size_t)8 * 16384 * 4);
  float* lpartX  = (float*)alloc((size_t)8 * 16384 * 4);
  // loop scratch region
  float* om2a   = (float*)alloc((size_t)1048576 * 4);
  bf16*  h_bf   = (bf16*)alloc((size_t)1048576 * 2);
  bf16*  u_bf   = (bf16*)alloc((size_t)2883584 * 2);
  float* om2P   = (float*)alloc((size_t)4 * 1048576 * 4);  // 4 split-K planes
  bf16*  om2_bf = (bf16*)alloc((size_t)1048576 * 2);
  f16*   k_mem  = (f16*)alloc((size_t)1048576 * 2);
  f16*   v_memT = (f16*)alloc((size_t)1048576 * 2);

  dim3 tb(256);
  probe_dtype<<<1, 64, 0, stream>>>(x, flag);

  // 7 DxD weight transposes in one launch
  transpose_cast_d7<<<dim3(32, 32, 7), tb, 0, stream>>>(
      wq, wk, wv, wm, wkm, wvm, wo, wqkvT, wmT, wkmvmT, woT, flag);
  // interleaved: w13T row 2j = w1 col j, row 2j+1 = w3 col j
  transpose_cast<<<dim3(88, 32), tb, 0, stream>>>(w1, w13T, 1024, 2816, flag, 2, 0);
  transpose_cast<<<dim3(88, 32), tb, 0, stream>>>(w3, w13T, 1024, 2816, flag, 2, 1);
  transpose_cast<<<dim3(32, 88), tb, 0, stream>>>(w2, w2T, 2816, 1024, flag, 1, 0);

  cast_to_bf16<<<32768, tb, 0, stream>>>(x, xb, 8388608, flag);
  cast_to_f32<<<128, tb, 0, stream>>>(fc, cosf, 32768, flag);
  cast_to_f32<<<128, tb, 0, stream>>>(fs, sinf, 32768, flag);
  cast_to_f32<<<4, tb, 0, stream>>>(fnw, ffnw, 1024, flag);
  cast_to_f32<<<4, tb, 0, stream>>>(mnw, memw, 1024, flag);
  init_om<<<4096, tb, 0, stream>>>(om0, om_bf, flag);

  // hoisted qkv GEMM with fused rope/transpose epilogue (out_mode 4)
  gemm128<<<dim3(24, 64), tb, 0, stream>>>(xb, wqkvT, nullptr, flag, 3072, 1024, 4,
                                           cosf, sinf, q_x, k_x, v_xT);
  // hoisted x-side causal attention for ALL steps (scan-invariant)
  attn_x<<<dim3(8, 32, 8), tb, 0, stream>>>(q_x, k_x, v_xT, OpartX, mpartX, lpartX);

  for (int t = 0; t < NSTEP; ++t) {
    // om2 partials (split-K=2) -> om2P planes 0,1
    gemm64_sk<<<dim3(16, 16, 2), tb, 0, stream>>>(om_bf, wmT, om2P, 1024, 1024, 512);
    // h = rmsnorm(p0+p1, ffnw); om2a = p0+p1
    rmsnorm_cast<<<1024, tb, 0, stream>>>(nullptr, ffnw, h_bf, om2P, 2, om2a);
    // u = silu(h@w1) * (h@w3), fused epilogue; 64x128 tile -> 704 blocks
    gemm64x128_silu<<<dim3(44, 16), tb, 0, stream>>>(h_bf, w13T, u_bf, 1024);
    // ffn-out partials (split-K=4) -> om2P planes 0..3
    gemm64_sk<<<dim3(16, 16, 4), tb, 0, stream>>>(u_bf, w2T, om2P, 1024, 2816, 704);
    // om2' = rmsnorm(om2a + p0..p3, memw)
    rmsnorm_cast<<<1024, tb, 0, stream>>>(om2a, memw, om2_bf, om2P, 4, nullptr);
    // mkv = om2' @ [wkm|wvm] with fused rope (K) / transpose (V)
    gemm64_kmvm<<<dim3(32, 16), tb, 0, stream>>>(om2_bf, wkmvmT, cosf, sinf, k_mem, v_memT);
    // memory-half attention + fused merge with x partials
    attn_mem<<<dim3(8, 32), tb, 0, stream>>>(q_x, k_mem, v_memT,
                                             OpartX + ((size_t)t << 20),
                                             mpartX + (size_t)t * 16384,
                                             lpartX + (size_t)t * 16384,
                                             om_bf, outs_bf, t);
  }
  gemm128<<<dim3(8, 64), tb, 0, stream>>>(outs_bf, woT, d_out, flag, 1024, 1024, 2,
                                          nullptr, nullptr, nullptr, nullptr, nullptr);
}

// Round 18
// 1021.719 us; speedup vs baseline: 1.0124x; 1.0124x over previous
//
#include <hip/hip_runtime.h>
#include <hip/hip_bf16.h>

// B=2, S=4096, D=1024, H=16, HD=64, M=512, L=1024, HID=2816, 8 scan steps.
// R15 = exact revert to R13 (verified 1022us). R14's w2 split-K=4 regressed
// to 1034us: +16MB/step partial traffic (+5us BW) + worse K-amortization
// outweighed the occupancy gain on a 17us dispatch. Split-K=2 is optimal for
// these 1024x1024-output GEMMs. Session ladder: 1276 -> 1150 -> 1140 -> 1132
// -> 1125 -> 1100 -> 1099 -> 1022 us.

#define D_    1024
#define H_    16
#define HD_   64
#define M_    512
#define L_    1024
#define HID_  2816
#define NSTEP 8

typedef __hip_bfloat16 bf16;
typedef _Float16 f16;
typedef __attribute__((ext_vector_type(8))) short short8;
typedef __attribute__((ext_vector_type(8))) _Float16 f16x8;
typedef __attribute__((ext_vector_type(4))) _Float16 f16x4;
typedef __attribute__((ext_vector_type(2))) _Float16 f16x2;
typedef __attribute__((ext_vector_type(4))) float floatx4;

// ---------------- dtype probe ----------------
__global__ void probe_dtype(const void* x, int* flag) {
  int lane = threadIdx.x;
  unsigned short v = ((const unsigned short*)x)[2 * lane];
  int e = (v >> 7) & 0xFF;
  bool sane = (e >= 100 && e <= 140);
  unsigned long long m = __ballot(sane);
  if (lane == 0) flag[0] = (__popcll(m) >= 40) ? 1 : 0;  // 1 = bf16 inputs
}

__device__ __forceinline__ float load_any(const void* p, long i, int isbf) {
  return isbf ? __bfloat162float(((const bf16*)p)[i]) : ((const float*)p)[i];
}

// ---------------- converts ----------------
// dest row = n*stride + off  (stride=2 interleaves w1/w3 columns)
__global__ __launch_bounds__(256) void transpose_cast(const void* in, bf16* out,
                                                      int K, int N, const int* flagp,
                                                      int stride, int off) {
  __shared__ float tile[32][33];
  int isbf = flagp[0];
  int tx = threadIdx.x & 31, ty = threadIdx.x >> 5;
  int n = blockIdx.x * 32 + tx;
#pragma unroll
  for (int i = 0; i < 4; i++) {
    int k = blockIdx.y * 32 + ty + i * 8;
    tile[ty + i * 8][tx] = load_any(in, (long)k * N + n, isbf);
  }
  __syncthreads();
  int k2 = blockIdx.y * 32 + tx;
#pragma unroll
  for (int i = 0; i < 4; i++) {
    int n2 = blockIdx.x * 32 + ty + i * 8;
    out[((long)n2 * stride + off) * K + k2] = __float2bfloat16(tile[tx][ty + i * 8]);
  }
}

// batched 1024x1024 transposes: z picks (src,dst) pair.
__global__ __launch_bounds__(256) void transpose_cast_d7(
    const void* wq, const void* wk, const void* wv, const void* wm,
    const void* wkm, const void* wvm, const void* wo,
    bf16* wqkvT, bf16* wmT, bf16* wkmvmT, bf16* woT, const int* flagp) {
  __shared__ float tile[32][33];
  int z = blockIdx.z;
  const void* in;
  bf16* out;
  switch (z) {
    case 0: in = wq;  out = wqkvT;               break;
    case 1: in = wk;  out = wqkvT + 1048576;     break;
    case 2: in = wv;  out = wqkvT + 2 * 1048576; break;
    case 3: in = wm;  out = wmT;                 break;
    case 4: in = wkm; out = wkmvmT;              break;
    case 5: in = wvm; out = wkmvmT + 1048576;    break;
    default: in = wo; out = woT;                 break;
  }
  int isbf = flagp[0];
  int tx = threadIdx.x & 31, ty = threadIdx.x >> 5;
  int n = blockIdx.x * 32 + tx;
#pragma unroll
  for (int i = 0; i < 4; i++) {
    int k = blockIdx.y * 32 + ty + i * 8;
    tile[ty + i * 8][tx] = load_any(in, (long)k * 1024 + n, isbf);
  }
  __syncthreads();
  int k2 = blockIdx.y * 32 + tx;
#pragma unroll
  for (int i = 0; i < 4; i++) {
    int n2 = blockIdx.x * 32 + ty + i * 8;
    out[(long)n2 * 1024 + k2] = __float2bfloat16(tile[tx][ty + i * 8]);
  }
}

__global__ __launch_bounds__(256) void cast_to_bf16(const void* in, bf16* out, int n,
                                                    const int* flagp) {
  int i = blockIdx.x * 256 + threadIdx.x;
  if (i < n) out[i] = __float2bfloat16(load_any(in, i, flagp[0]));
}

__global__ __launch_bounds__(256) void cast_to_f32(const void* in, float* out, int n,
                                                   const int* flagp) {
  int i = blockIdx.x * 256 + threadIdx.x;
  if (i < n) out[i] = load_any(in, i, flagp[0]);
}

__global__ __launch_bounds__(256) void init_om(const void* in, bf16* om, const int* flagp) {
  int i = blockIdx.x * 256 + threadIdx.x;  // 1048576
  int rem = i & (M_ * D_ - 1);
  om[i] = __float2bfloat16(load_any(in, rem, flagp[0]));
}

// ---------------- 64x64 MFMA GEMM core (shared macro body) ----------------
#define GEMM64_BODY(Aptr, WTptr, Kld, kbeg, kend)                                   \
  __shared__ char smem[16384];                                                      \
  char* aT = smem;                                                                  \
  char* bT = smem + 8192;                                                           \
  int tid = threadIdx.x;                                                            \
  int wave = tid >> 6, lane = tid & 63;                                             \
  int wm_ = wave >> 1, wn_ = wave & 1;                                              \
  floatx4 acc[2][2] = {};                                                           \
  int q0 = tid, q1 = tid + 256;                                                     \
  int am0 = q0 >> 3, ac0 = q0 & 7;                                                  \
  int am1 = q1 >> 3, ac1 = q1 & 7;                                                  \
  long grow0 = R0 + am0, grow1 = R0 + am1;                                          \
  long bn0 = (long)(C0 + am0) * (Kld), bn1 = (long)(C0 + am1) * (Kld);              \
  int lofa0 = (am0 * 8 + (ac0 ^ (am0 & 7))) * 16;                                   \
  int lofa1 = (am1 * 8 + (ac1 ^ (am1 & 7))) * 16;                                   \
  for (int k0 = (kbeg); k0 < (kend); k0 += 64) {                                    \
    uint4 va0 = *(const uint4*)((Aptr) + grow0 * (Kld) + k0 + ac0 * 8);             \
    uint4 va1 = *(const uint4*)((Aptr) + grow1 * (Kld) + k0 + ac1 * 8);             \
    uint4 vb0 = *(const uint4*)((WTptr) + bn0 + k0 + ac0 * 8);                      \
    uint4 vb1 = *(const uint4*)((WTptr) + bn1 + k0 + ac1 * 8);                      \
    __syncthreads();                                                                \
    *(uint4*)(aT + lofa0) = va0;                                                    \
    *(uint4*)(aT + lofa1) = va1;                                                    \
    *(uint4*)(bT + lofa0) = vb0;                                                    \
    *(uint4*)(bT + lofa1) = vb1;                                                    \
    __syncthreads();                                                                \
    _Pragma("unroll") for (int kki = 0; kki < 2; ++kki) {                           \
      int cbase = kki * 4 + (lane >> 4);                                            \
      short8 af[2], bfr[2];                                                         \
      _Pragma("unroll") for (int i = 0; i < 2; ++i) {                               \
        int ml = wm_ * 32 + i * 16 + (lane & 15);                                   \
        af[i] = *(const short8*)(aT + (ml * 8 + (cbase ^ (ml & 7))) * 16);          \
        int nl = wn_ * 32 + i * 16 + (lane & 15);                                   \
        bfr[i] = *(const short8*)(bT + (nl * 8 + (cbase ^ (nl & 7))) * 16);         \
      }                                                                             \
      _Pragma("unroll") for (int i = 0; i < 2; ++i)                                 \
          _Pragma("unroll") for (int j = 0; j < 2; ++j) acc[i][j] =                 \
              __builtin_amdgcn_mfma_f32_16x16x32_bf16(af[i], bfr[j], acc[i][j],     \
                                                      0, 0, 0);                     \
    }                                                                               \
  }

// split-K via blockIdx.z: plane z -> outP + z*2^20 (all uses are 1024x1024 out).
__global__ __launch_bounds__(256) void gemm64_sk(
    const bf16* __restrict__ A, const bf16* __restrict__ WT,
    float* __restrict__ outP, int N, int Kfull, int Ksplit) {
  int C0 = blockIdx.x * 64, R0 = blockIdx.y * 64;
  int kb = blockIdx.z;
  float* out = outP + ((size_t)kb << 20);
  int kbeg = kb * Ksplit;
  GEMM64_BODY(A, WT, Kfull, kbeg, kbeg + Ksplit)
#pragma unroll
  for (int i = 0; i < 2; ++i)
#pragma unroll
    for (int j = 0; j < 2; ++j) {
      int row = R0 + wm_ * 32 + i * 16 + (lane >> 4) * 4;
      int col = C0 + wn_ * 32 + j * 16 + (lane & 15);
#pragma unroll
      for (int rg = 0; rg < 4; ++rg)
        out[(long)(row + rg) * N + col] = acc[i][j][rg];
    }
}

// kmvm GEMM (om2 @ [wkm|wvm], N=2048, K=1024) with fused rope (K side) and
// transpose (V side). Rows = b*512+pos; cols 0..1023 -> k_mem, 1024.. -> v_memT.
__global__ __launch_bounds__(256) void gemm64_kmvm(
    const bf16* __restrict__ A, const bf16* __restrict__ WT,
    const float* __restrict__ cosf, const float* __restrict__ sinf,
    f16* __restrict__ k_mem, f16* __restrict__ v_memT) {
  int C0 = blockIdx.x * 64, R0 = blockIdx.y * 64;
  GEMM64_BODY(A, WT, 1024, 0, 1024)
#pragma unroll
  for (int i = 0; i < 2; ++i)
#pragma unroll
    for (int j = 0; j < 2; ++j) {
      int row0 = R0 + wm_ * 32 + i * 16 + (lane >> 4) * 4;
      int col = C0 + wn_ * 32 + j * 16 + (lane & 15);
#pragma unroll
      for (int rg = 0; rg < 4; ++rg) {
        float v = acc[i][j][rg];
        int row = row0 + rg;
        int b = row >> 9, pos = row & 511;
        if (C0 < 1024) {
          // K side: rope pair (2i,2i+1) sits in adjacent lanes
          float partner = __shfl_xor(v, 1);
          int ii = (col & 63) >> 1;
          float c = cosf[pos * 32 + ii], s = sinf[pos * 32 + ii];
          float o = (col & 1) ? (partner * s + v * c) : (v * c - partner * s);
          int bh = b * 16 + ((col >> 6) & 15);
          k_mem[((size_t)bh * 512 + pos) * 64 + (col & 63)] = (f16)o;
        } else {
          int d = col & 63;
          int bh = b * 16 + ((col - 1024) >> 6);
          v_memT[((size_t)bh * 64 + d) * 512 + pos] = (f16)v;
        }
      }
    }
}

// ---------------- 128x128 MFMA GEMM, global_load_lds (m97 structure) --------
// out_mode: 1 = f16, 2 = per flag, 4 = fused qkv rope/transpose.
__global__ __launch_bounds__(256) void gemm128(
    const bf16* __restrict__ A, const bf16* __restrict__ WT,
    void* __restrict__ out, const int* __restrict__ flagp,
    int N, int K, int out_mode,
    const float* __restrict__ cosf, const float* __restrict__ sinf,
    f16* __restrict__ q_x, f16* __restrict__ k_x, f16* __restrict__ v_xT) {
  __shared__ char smem[32768];  // A 16K | B 16K
  int tid = threadIdx.x;
  int w = tid >> 6, lane = tid & 63;
  int C0 = blockIdx.x * 128, R0 = blockIdx.y * 128;
  int wm = (w >> 1) * 64, wn = (w & 1) * 64;
  int g = lane >> 4, n16 = lane & 15;
  floatx4 acc[4][4] = {};
  int lr = lane >> 3, lc = lane & 7;

  for (int k0 = 0; k0 < K; k0 += 64) {
    __syncthreads();
#pragma unroll
    for (int i = 0; i < 4; ++i) {
      int m = w * 32 + i * 8 + lr;
      int cg = lc ^ (m & 7);
      const bf16* ga = A + (size_t)(R0 + m) * K + k0 + cg * 8;
      const bf16* gb = WT + (size_t)(C0 + m) * K + k0 + cg * 8;
      __builtin_amdgcn_global_load_lds(
          (const __attribute__((address_space(1))) void*)ga,
          (__attribute__((address_space(3))) void*)(smem + (w * 32 + i * 8) * 128),
          16, 0, 0);
      __builtin_amdgcn_global_load_lds(
          (const __attribute__((address_space(1))) void*)gb,
          (__attribute__((address_space(3))) void*)(smem + 16384 + (w * 32 + i * 8) * 128),
          16, 0, 0);
    }
    __syncthreads();
#pragma unroll
    for (int kk = 0; kk < 2; ++kk) {
      short8 af[4], bfr[4];
#pragma unroll
      for (int i = 0; i < 4; ++i) {
        int ml = wm + i * 16 + n16;
        af[i] = *(const short8*)(smem + (ml * 8 + ((kk * 4 + g) ^ (ml & 7))) * 16);
        int nl = wn + i * 16 + n16;
        bfr[i] = *(const short8*)(smem + 16384 + (nl * 8 + ((kk * 4 + g) ^ (nl & 7))) * 16);
      }
#pragma unroll
      for (int i = 0; i < 4; ++i)
#pragma unroll
        for (int j = 0; j < 4; ++j)
          acc[i][j] = __builtin_amdgcn_mfma_f32_16x16x32_bf16(af[i], bfr[j], acc[i][j], 0, 0, 0);
    }
  }
  int isbf = flagp ? flagp[0] : 0;
#pragma unroll
  for (int i = 0; i < 4; ++i)
#pragma unroll
    for (int j = 0; j < 4; ++j) {
      int row = R0 + wm + i * 16 + g * 4;
      int col = C0 + wn + j * 16 + n16;
      if (out_mode == 4) {
        // rows: b*4096 + t*512 + m; cols: [0,1024)=q, [1024,2048)=k, rest=v
        if (col < 2048) {
#pragma unroll
          for (int rg = 0; rg < 4; ++rg) {
            float v = acc[i][j][rg];
            float partner = __shfl_xor(v, 1);
            int r = row + rg;
            int m = r & 511, t = (r >> 9) & 7, b = r >> 12;
            int pos = 512 + m;
            int ii = (col & 63) >> 1;
            float c = cosf[pos * 32 + ii], s = sinf[pos * 32 + ii];
            float o = (col & 1) ? (partner * s + v * c) : (v * c - partner * s);
            int h = (col >> 6) & 15;
            size_t slab = (size_t)t * 32 + b * 16 + h;
            if (col < 1024)
              q_x[(slab * 512 + m) * 64 + (col & 63)] = (f16)(o * 0.125f);
            else
              k_x[(slab * 512 + m) * 64 + (col & 63)] = (f16)o;
          }
        } else {
          int r = row;
          int m = r & 511, t = (r >> 9) & 7, b = r >> 12;
          int d = col & 63, h = (col - 2048) >> 6;
          size_t slab = (size_t)t * 32 + b * 16 + h;
          f16x4 vv;
#pragma unroll
          for (int rg = 0; rg < 4; ++rg) vv[rg] = (f16)acc[i][j][rg];
          *(f16x4*)(v_xT + (slab * 64 + d) * 512 + m) = vv;
        }
        continue;
      }
#pragma unroll
      for (int rg = 0; rg < 4; ++rg) {
        float v = acc[i][j][rg];
        long off = (long)(row + rg) * N + col;
        if (out_mode == 1) ((f16*)out)[off] = (f16)v;
        else {
          if (isbf) ((bf16*)out)[off] = __float2bfloat16(v);
          else ((float*)out)[off] = v;
        }
      }
    }
}

// ---------------- 64x128 MFMA GEMM with fused silu-mul (w13 only) ----------
// BM=64 rows, BN=128 interleaved cols -> grid (44,16) = 704 blocks (2.75/CU).
// Same m97 staging/swizzle formulas; LDS 24KB (A 8K | B 16K).
__global__ __launch_bounds__(256) void gemm64x128_silu(
    const bf16* __restrict__ A, const bf16* __restrict__ WT,
    bf16* __restrict__ out, int K) {
  __shared__ char smem[24576];  // A 8K | B 16K
  int tid = threadIdx.x;
  int w = tid >> 6, lane = tid & 63;
  int C0 = blockIdx.x * 128, R0 = blockIdx.y * 64;
  int wm = (w >> 1) * 32, wn = (w & 1) * 64;
  int g = lane >> 4, n16 = lane & 15;
  floatx4 acc[2][4] = {};
  int lr = lane >> 3, lc = lane & 7;

  for (int k0 = 0; k0 < K; k0 += 64) {
    __syncthreads();
    // A tile: 64 rows; wave w stages rows w*16 .. w*16+15 (2 issues of 8 rows)
#pragma unroll
    for (int i = 0; i < 2; ++i) {
      int m = w * 16 + i * 8 + lr;
      int cg = lc ^ (m & 7);
      const bf16* ga = A + (size_t)(R0 + m) * K + k0 + cg * 8;
      __builtin_amdgcn_global_load_lds(
          (const __attribute__((address_space(1))) void*)ga,
          (__attribute__((address_space(3))) void*)(smem + (w * 16 + i * 8) * 128),
          16, 0, 0);
    }
    // B tile: 128 rows; wave w stages rows w*32 .. w*32+31 (4 issues)
#pragma unroll
    for (int i = 0; i < 4; ++i) {
      int m = w * 32 + i * 8 + lr;
      int cg = lc ^ (m & 7);
      const bf16* gb = WT + (size_t)(C0 + m) * K + k0 + cg * 8;
      __builtin_amdgcn_global_load_lds(
          (const __attribute__((address_space(1))) void*)gb,
          (__attribute__((address_space(3))) void*)(smem + 8192 + (w * 32 + i * 8) * 128),
          16, 0, 0);
    }
    __syncthreads();
#pragma unroll
    for (int kk = 0; kk < 2; ++kk) {
      short8 af[2], bfr[4];
#pragma unroll
      for (int i = 0; i < 2; ++i) {
        int ml = wm + i * 16 + n16;
        af[i] = *(const short8*)(smem + (ml * 8 + ((kk * 4 + g) ^ (ml & 7))) * 16);
      }
#pragma unroll
      for (int j = 0; j < 4; ++j) {
        int nl = wn + j * 16 + n16;
        bfr[j] = *(const short8*)(smem + 8192 + (nl * 8 + ((kk * 4 + g) ^ (nl & 7))) * 16);
      }
#pragma unroll
      for (int i = 0; i < 2; ++i)
#pragma unroll
        for (int j = 0; j < 4; ++j)
          acc[i][j] = __builtin_amdgcn_mfma_f32_16x16x32_bf16(af[i], bfr[j], acc[i][j], 0, 0, 0);
    }
  }
  // fused silu-mul epilogue: (g1,g3) pair sits in adjacent lanes (even/odd n16)
#pragma unroll
  for (int i = 0; i < 2; ++i)
#pragma unroll
    for (int j = 0; j < 4; ++j) {
      int row = R0 + wm + i * 16 + g * 4;
      int col = C0 + wn + j * 16 + n16;
#pragma unroll
      for (int rg = 0; rg < 4; ++rg) {
        float v = acc[i][j][rg];
        float partner = __shfl_xor(v, 1);
        if ((n16 & 1) == 0) {
          float a = v;
          float s = a / (1.f + __expf(-a));
          out[(long)(row + rg) * HID_ + (col >> 1)] = __float2bfloat16(s * partner);
        }
      }
    }
}

// ---------------- elementwise ----------------
// v = (X?X:0) + sum_{k<np} P[k<<20 + .]; Y = rmsnorm(v, Wn); sumout? = v.
__global__ __launch_bounds__(256) void rmsnorm_cast(const float* __restrict__ X,
                                                    const float* __restrict__ Wn,
                                                    bf16* __restrict__ Y,
                                                    const float* __restrict__ P,
                                                    int np,
                                                    float* __restrict__ sumout) {
  int row = blockIdx.x, tid = threadIdx.x;
  float vals[4], ss = 0.f;
#pragma unroll
  for (int i = 0; i < 4; i++) {
    int c = tid + i * 256;
    long idx = (long)row * D_ + c;
    float v = X ? X[idx] : 0.f;
    for (int k = 0; k < np; ++k) v += P[((size_t)k << 20) + idx];
    vals[i] = v;
    ss += v * v;
  }
#pragma unroll
  for (int off = 32; off; off >>= 1) ss += __shfl_xor(ss, off);
  __shared__ float wsum[4];
  int wv = tid >> 6, lane = tid & 63;
  if (lane == 0) wsum[wv] = ss;
  __syncthreads();
  ss = wsum[0] + wsum[1] + wsum[2] + wsum[3];
  float r = rsqrtf(ss * (1.0f / D_) + 1e-5f);
#pragma unroll
  for (int i = 0; i < 4; i++) {
    int c = tid + i * 256;
    if (sumout) sumout[(long)row * D_ + c] = vals[i];
    Y[(long)row * D_ + c] = __float2bfloat16(vals[i] * r * Wn[c]);
  }
}

// ---------------- fp16 MFMA flash attention ----------------
// attn_x: x-side causal half for ALL steps (scan-invariant), hoisted upfront.
// grid (8 qt, 32 bh, 8 t). Writes unnormalized partials + (m,l) per t.
__global__ __launch_bounds__(256) void attn_x(
    const f16* __restrict__ q_x, const f16* __restrict__ k_x,
    const f16* __restrict__ v_xT, float* __restrict__ OpartX,
    float* __restrict__ mpartX, float* __restrict__ lpartX) {
  __shared__ char smem[40960];  // K dbuf 2x8K | V^T dbuf 2x8K | P 4x2K
  int qt = blockIdx.x, bh = blockIdx.y, t = blockIdx.z;
  int tid = threadIdx.x;
  int w = tid >> 6, lane = tid & 63;
  int g = lane >> 4, n16 = lane & 15;
  int numc = qt + 1;
  int pos = 512 + qt * 64 + w * 16 + n16;
  size_t slab = (size_t)t * 32 + bh;

  f16x8 qf[2];
  {
    const f16* qp = q_x + (slab * 512 + qt * 64 + w * 16 + n16) * 64 + g * 8;
    qf[0] = *(const f16x8*)(qp);
    qf[1] = *(const f16x8*)(qp + 32);
  }
  floatx4 O[4] = {};
  float mrun = -1e30f, lrun = 0.f;

  int id0 = tid, id1 = tid + 256;
  int r0 = id0 >> 3, cc0 = id0 & 7;
  int r1 = id1 >> 3, cc1 = id1 & 7;
  int lof0 = ((r0 << 3) | (cc0 ^ (r0 & 7))) * 16;
  int lof1 = ((r1 << 3) | (cc1 ^ (r1 & 7))) * 16;

  uint4 kv0 = *(const uint4*)(k_x + (slab * 512 + r0) * 64 + cc0 * 8);
  uint4 kv1 = *(const uint4*)(k_x + (slab * 512 + r1) * 64 + cc1 * 8);
  uint4 vv0 = *(const uint4*)(v_xT + (slab * 64 + r0) * 512 + cc0 * 8);
  uint4 vv1 = *(const uint4*)(v_xT + (slab * 64 + r1) * 512 + cc1 * 8);

  char* Pw = smem + 32768 + w * 2048;

  for (int c = 0; c < numc; ++c) {
    char* Kb = smem + (c & 1) * 8192;
    char* Vb = smem + 16384 + (c & 1) * 8192;
    *(uint4*)(Kb + lof0) = kv0;
    *(uint4*)(Kb + lof1) = kv1;
    *(uint4*)(Vb + lof0) = vv0;
    *(uint4*)(Vb + lof1) = vv1;
    if (c + 1 < numc) {
      int ca = c + 1;
      kv0 = *(const uint4*)(k_x + (slab * 512 + ca * 64 + r0) * 64 + cc0 * 8);
      kv1 = *(const uint4*)(k_x + (slab * 512 + ca * 64 + r1) * 64 + cc1 * 8);
      vv0 = *(const uint4*)(v_xT + (slab * 64 + r0) * 512 + ca * 64 + cc0 * 8);
      vv1 = *(const uint4*)(v_xT + (slab * 64 + r1) * 512 + ca * 64 + cc1 * 8);
    }
    __syncthreads();

    floatx4 S[4] = {};
    __builtin_amdgcn_s_setprio(1);
#pragma unroll
    for (int kk = 0; kk < 2; ++kk) {
#pragma unroll
      for (int tn = 0; tn < 4; ++tn) {
        int row = tn * 16 + n16;
        f16x8 kf = *(const f16x8*)(Kb + (((row << 3) | ((kk * 4 + g) ^ (row & 7))) * 16));
        S[tn] = __builtin_amdgcn_mfma_f32_16x16x32_f16(kf, qf[kk], S[tn], 0, 0, 0);
      }
    }
    __builtin_amdgcn_s_setprio(0);
    if (c == numc - 1) {
      int kb = 512 + qt * 64;
#pragma unroll
      for (int tn = 0; tn < 4; ++tn)
#pragma unroll
        for (int r = 0; r < 4; ++r) {
          int key = kb + tn * 16 + g * 4 + r;
          if (key > pos) S[tn][r] = -1e30f;
        }
    }
    float smax = -1e30f;
#pragma unroll
    for (int tn = 0; tn < 4; ++tn)
#pragma unroll
      for (int r = 0; r < 4; ++r) smax = fmaxf(smax, S[tn][r]);
    smax = fmaxf(smax, __shfl_xor(smax, 16));
    smax = fmaxf(smax, __shfl_xor(smax, 32));
    float corr = 1.f;
    if (__any(smax > mrun + 8.f)) {
      float newm = fmaxf(mrun, smax);
      corr = __expf(mrun - newm);
      mrun = newm;
      float cr[4];
#pragma unroll
      for (int r = 0; r < 4; ++r) cr[r] = __shfl(corr, g * 4 + r);
#pragma unroll
      for (int dt = 0; dt < 4; ++dt)
#pragma unroll
        for (int r = 0; r < 4; ++r) O[dt][r] *= cr[r];
    }
    float lsum = 0.f;
#pragma unroll
    for (int tn = 0; tn < 4; ++tn) {
      f16x4 pk;
#pragma unroll
      for (int r = 0; r < 4; ++r) {
        float p = __expf(S[tn][r] - mrun);
        lsum += p;
        pk[r] = (f16)p;
      }
      int kapb = tn * 16 + g * 4;
      *(f16x4*)(Pw + (((n16 << 3) | ((kapb >> 3) ^ (n16 & 7))) * 16 + (kapb & 7) * 2)) = pk;
    }
    lsum += __shfl_xor(lsum, 16);
    lsum += __shfl_xor(lsum, 32);
    lrun = lrun * corr + lsum;
    __builtin_amdgcn_s_setprio(1);
#pragma unroll
    for (int kk = 0; kk < 2; ++kk) {
      f16x8 pf = *(const f16x8*)(Pw + (((n16 << 3) | ((kk * 4 + g) ^ (n16 & 7))) * 16));
#pragma unroll
      for (int dt = 0; dt < 4; ++dt) {
        int row = dt * 16 + n16;
        f16x8 vf =
            *(const f16x8*)(Vb + (((row << 3) | ((kk * 4 + g) ^ (row & 7))) * 16));
        O[dt] = __builtin_amdgcn_mfma_f32_16x16x32_f16(pf, vf, O[dt], 0, 0, 0);
      }
    }
    __builtin_amdgcn_s_setprio(0);
    __syncthreads();
  }
  int b = bh >> 4, h = bh & 15;
  if (g == 0) {
    int qq = qt * 64 + w * 16 + n16;
    mpartX[(size_t)t * 16384 + bh * 512 + qq] = mrun;
    lpartX[(size_t)t * 16384 + bh * 512 + qq] = lrun;
  }
#pragma unroll
  for (int dt = 0; dt < 4; ++dt)
#pragma unroll
    for (int r = 0; r < 4; ++r) {
      int qq = qt * 64 + w * 16 + g * 4 + r;
      size_t col = (size_t)h * 64 + dt * 16 + n16;
      OpartX[((size_t)t << 20) + (size_t)(b * 512 + qq) * 1024 + col] = O[dt][r];
    }
}

// attn_mem: memory half (8 chunks, no mask) + fused merge with x partials.
// grid (8 qt, 32 bh). Writes om_bf + outs_bf directly.
__global__ __launch_bounds__(256) void attn_mem(
    const f16* __restrict__ q_x, const f16* __restrict__ k_mem,
    const f16* __restrict__ v_memT, const float* __restrict__ OX,
    const float* __restrict__ mX, const float* __restrict__ lX,
    bf16* __restrict__ om_bf, bf16* __restrict__ outs_bf, int t) {
  __shared__ char smem[40960];  // K dbuf 2x8K | V^T dbuf 2x8K | P 4x2K
  int qt = blockIdx.x, bh = blockIdx.y;
  int tid = threadIdx.x;
  int w = tid >> 6, lane = tid & 63;
  int g = lane >> 4, n16 = lane & 15;
  size_t slab = (size_t)t * 32 + bh;

  f16x8 qf[2];
  {
    const f16* qp = q_x + (slab * 512 + qt * 64 + w * 16 + n16) * 64 + g * 8;
    qf[0] = *(const f16x8*)(qp);
    qf[1] = *(const f16x8*)(qp + 32);
  }
  floatx4 O[4] = {};
  float mrun = -1e30f, lrun = 0.f;

  int id0 = tid, id1 = tid + 256;
  int r0 = id0 >> 3, cc0 = id0 & 7;
  int r1 = id1 >> 3, cc1 = id1 & 7;
  int lof0 = ((r0 << 3) | (cc0 ^ (r0 & 7))) * 16;
  int lof1 = ((r1 << 3) | (cc1 ^ (r1 & 7))) * 16;

  uint4 kv0 = *(const uint4*)(k_mem + ((size_t)bh * 512 + r0) * 64 + cc0 * 8);
  uint4 kv1 = *(const uint4*)(k_mem + ((size_t)bh * 512 + r1) * 64 + cc1 * 8);
  uint4 vv0 = *(const uint4*)(v_memT + ((size_t)bh * 64 + r0) * 512 + cc0 * 8);
  uint4 vv1 = *(const uint4*)(v_memT + ((size_t)bh * 64 + r1) * 512 + cc1 * 8);

  char* Pw = smem + 32768 + w * 2048;

  for (int c = 0; c < 8; ++c) {
    char* Kb = smem + (c & 1) * 8192;
    char* Vb = smem + 16384 + (c & 1) * 8192;
    *(uint4*)(Kb + lof0) = kv0;
    *(uint4*)(Kb + lof1) = kv1;
    *(uint4*)(Vb + lof0) = vv0;
    *(uint4*)(Vb + lof1) = vv1;
    if (c + 1 < 8) {
      int ca = c + 1;
      kv0 = *(const uint4*)(k_mem + ((size_t)bh * 512 + ca * 64 + r0) * 64 + cc0 * 8);
      kv1 = *(const uint4*)(k_mem + ((size_t)bh * 512 + ca * 64 + r1) * 64 + cc1 * 8);
      vv0 = *(const uint4*)(v_memT + ((size_t)bh * 64 + r0) * 512 + ca * 64 + cc0 * 8);
      vv1 = *(const uint4*)(v_memT + ((size_t)bh * 64 + r1) * 512 + ca * 64 + cc1 * 8);
    }
    __syncthreads();

    floatx4 S[4] = {};
    __builtin_amdgcn_s_setprio(1);
#pragma unroll
    for (int kk = 0; kk < 2; ++kk) {
#pragma unroll
      for (int tn = 0; tn < 4; ++tn) {
        int row = tn * 16 + n16;
        f16x8 kf = *(const f16x8*)(Kb + (((row << 3) | ((kk * 4 + g) ^ (row & 7))) * 16));
        S[tn] = __builtin_amdgcn_mfma_f32_16x16x32_f16(kf, qf[kk], S[tn], 0, 0, 0);
      }
    }
    __builtin_amdgcn_s_setprio(0);
    float smax = -1e30f;
#pragma unroll
    for (int tn = 0; tn < 4; ++tn)
#pragma unroll
      for (int r = 0; r < 4; ++r) smax = fmaxf(smax, S[tn][r]);
    smax = fmaxf(smax, __shfl_xor(smax, 16));
    smax = fmaxf(smax, __shfl_xor(smax, 32));
    float corr = 1.f;
    if (__any(smax > mrun + 8.f)) {
      float newm = fmaxf(mrun, smax);
      corr = __expf(mrun - newm);
      mrun = newm;
      float cr[4];
#pragma unroll
      for (int r = 0; r < 4; ++r) cr[r] = __shfl(corr, g * 4 + r);
#pragma unroll
      for (int dt = 0; dt < 4; ++dt)
#pragma unroll
        for (int r = 0; r < 4; ++r) O[dt][r] *= cr[r];
    }
    float lsum = 0.f;
#pragma unroll
    for (int tn = 0; tn < 4; ++tn) {
      f16x4 pk;
#pragma unroll
      for (int r = 0; r < 4; ++r) {
        float p = __expf(S[tn][r] - mrun);
        lsum += p;
        pk[r] = (f16)p;
      }
      int kapb = tn * 16 + g * 4;
      *(f16x4*)(Pw + (((n16 << 3) | ((kapb >> 3) ^ (n16 & 7))) * 16 + (kapb & 7) * 2)) = pk;
    }
    lsum += __shfl_xor(lsum, 16);
    lsum += __shfl_xor(lsum, 32);
    lrun = lrun * corr + lsum;
    __builtin_amdgcn_s_setprio(1);
#pragma unroll
    for (int kk = 0; kk < 2; ++kk) {
      f16x8 pf = *(const f16x8*)(Pw + (((n16 << 3) | ((kk * 4 + g) ^ (n16 & 7))) * 16));
#pragma unroll
      for (int dt = 0; dt < 4; ++dt) {
        int row = dt * 16 + n16;
        f16x8 vf =
            *(const f16x8*)(Vb + (((row << 3) | ((kk * 4 + g) ^ (row & 7))) * 16));
        O[dt] = __builtin_amdgcn_mfma_f32_16x16x32_f16(pf, vf, O[dt], 0, 0, 0);
      }
    }
    __builtin_amdgcn_s_setprio(0);
    __syncthreads();
  }
  // fused merge with x-side partials
  int b = bh >> 4, h = bh & 15;
  float a1[4], a2[4], rden[4];
  int qqr[4];
#pragma unroll
  for (int r = 0; r < 4; ++r) {
    float m1 = __shfl(mrun, g * 4 + r);
    float l1 = __shfl(lrun, g * 4 + r);
    qqr[r] = qt * 64 + w * 16 + g * 4 + r;
    int idx = bh * 512 + qqr[r];
    float m2 = mX[idx], l2 = lX[idx];
    float Mx = fmaxf(m1, m2);
    a1[r] = __expf(m1 - Mx);
    a2[r] = __expf(m2 - Mx);
    rden[r] = 1.f / (a1[r] * l1 + a2[r] * l2);
  }
#pragma unroll
  for (int dt = 0; dt < 4; ++dt)
#pragma unroll
    for (int r = 0; r < 4; ++r) {
      size_t col = (size_t)h * 64 + dt * 16 + n16;
      size_t rowoff = (size_t)(b * 512 + qqr[r]) * 1024 + col;
      float o2 = OX[rowoff];
      float v = (a1[r] * O[dt][r] + a2[r] * o2) * rden[r];
      bf16 bv = __float2bfloat16(v);
      om_bf[rowoff] = bv;
      outs_bf[((size_t)(b * 4096 + t * 512 + qqr[r])) * 1024 + col] = bv;
    }
}

// ---------------- launch ----------------
extern "C" void kernel_launch(void* const* d_in, const int* in_sizes, int n_in,
                              void* d_out, int out_size, void* d_ws, size_t ws_size,
                              hipStream_t stream) {
  (void)in_sizes; (void)n_in; (void)out_size; (void)ws_size;
  const void* x   = d_in[0];
  const void* fc  = d_in[1];
  const void* fs  = d_in[2];
  const void* wq  = d_in[3];
  const void* wk  = d_in[4];
  const void* wv  = d_in[5];
  const void* wo  = d_in[6];
  const void* wm  = d_in[7];
  const void* wkm = d_in[8];
  const void* wvm = d_in[9];
  const void* w1  = d_in[10];
  const void* w3  = d_in[11];
  const void* w2  = d_in[12];
  const void* fnw = d_in[13];
  const void* mnw = d_in[14];
  const void* om0 = d_in[15];

  char* p = (char*)d_ws;
  auto alloc = [&](size_t bytes) -> char* {
    char* r = p;
    p += (bytes + 255) & ~(size_t)255;
    return r;
  };
  int*   flag    = (int*)alloc(256);
  bf16*  wqkvT   = (bf16*)alloc((size_t)3 * 1048576 * 2);
  bf16*  wmT     = (bf16*)alloc((size_t)1048576 * 2);
  bf16*  wkmvmT  = (bf16*)alloc((size_t)2 * 1048576 * 2);
  bf16*  w13T    = (bf16*)alloc((size_t)2 * 2883584 * 2);  // interleaved w1/w3
  bf16*  w2T     = (bf16*)alloc((size_t)2883584 * 2);
  bf16*  woT     = (bf16*)alloc((size_t)1048576 * 2);
  bf16*  xb      = (bf16*)alloc((size_t)8388608 * 2);
  float* cosf    = (float*)alloc((size_t)32768 * 4);
  float* sinf    = (float*)alloc((size_t)32768 * 4);
  float* ffnw    = (float*)alloc((size_t)1024 * 4);
  float* memw    = (float*)alloc((size_t)1024 * 4);
  bf16*  om_bf   = (bf16*)alloc((size_t)1048576 * 2);
  bf16*  outs_bf = (bf16*)alloc((size_t)8388608 * 2);
  f16*   q_x     = (f16*)alloc((size_t)8 * 32 * 512 * 64 * 2);
  f16*   k_x     = (f16*)alloc((size_t)8 * 32 * 512 * 64 * 2);
  f16*   v_xT    = (f16*)alloc((size_t)8 * 32 * 512 * 64 * 2);
  float* OpartX  = (float*)alloc((size_t)8 * 1048576 * 4);  // 32 MB x-partials
  float* mpartX  = (float*)alloc((size_t)8 * 16384 * 4);
  float* lpartX  = (float*)alloc((size_t)8 * 16384 * 4);
  // loop scratch region
  float* om2a   = (float*)alloc((size_t)1048576 * 4);
  bf16*  h_bf   = (bf16*)alloc((size_t)1048576 * 2);
  bf16*  u_bf   = (bf16*)alloc((size_t)2883584 * 2);
  float* om2P   = (float*)alloc((size_t)2 * 1048576 * 4);  // split-K planes
  bf16*  om2_bf = (bf16*)alloc((size_t)1048576 * 2);
  f16*   k_mem  = (f16*)alloc((size_t)1048576 * 2);
  f16*   v_memT = (f16*)alloc((size_t)1048576 * 2);

  dim3 tb(256);
  probe_dtype<<<1, 64, 0, stream>>>(x, flag);

  // 7 DxD weight transposes in one launch
  transpose_cast_d7<<<dim3(32, 32, 7), tb, 0, stream>>>(
      wq, wk, wv, wm, wkm, wvm, wo, wqkvT, wmT, wkmvmT, woT, flag);
  // interleaved: w13T row 2j = w1 col j, row 2j+1 = w3 col j
  transpose_cast<<<dim3(88, 32), tb, 0, stream>>>(w1, w13T, 1024, 2816, flag, 2, 0);
  transpose_cast<<<dim3(88, 32), tb, 0, stream>>>(w3, w13T, 1024, 2816, flag, 2, 1);
  transpose_cast<<<dim3(32, 88), tb, 0, stream>>>(w2, w2T, 2816, 1024, flag, 1, 0);

  cast_to_bf16<<<32768, tb, 0, stream>>>(x, xb, 8388608, flag);
  cast_to_f32<<<128, tb, 0, stream>>>(fc, cosf, 32768, flag);
  cast_to_f32<<<128, tb, 0, stream>>>(fs, sinf, 32768, flag);
  cast_to_f32<<<4, tb, 0, stream>>>(fnw, ffnw, 1024, flag);
  cast_to_f32<<<4, tb, 0, stream>>>(mnw, memw, 1024, flag);
  init_om<<<4096, tb, 0, stream>>>(om0, om_bf, flag);

  // hoisted qkv GEMM with fused rope/transpose epilogue (out_mode 4)
  gemm128<<<dim3(24, 64), tb, 0, stream>>>(xb, wqkvT, nullptr, flag, 3072, 1024, 4,
                                           cosf, sinf, q_x, k_x, v_xT);
  // hoisted x-side causal attention for ALL steps (scan-invariant)
  attn_x<<<dim3(8, 32, 8), tb, 0, stream>>>(q_x, k_x, v_xT, OpartX, mpartX, lpartX);

  for (int t = 0; t < NSTEP; ++t) {
    // om2 partials (split-K=2) -> om2P planes 0,1
    gemm64_sk<<<dim3(16, 16, 2), tb, 0, stream>>>(om_bf, wmT, om2P, 1024, 1024, 512);
    // h = rmsnorm(p0+p1, ffnw); om2a = p0+p1
    rmsnorm_cast<<<1024, tb, 0, stream>>>(nullptr, ffnw, h_bf, om2P, 2, om2a);
    // u = silu(h@w1) * (h@w3), fused epilogue; 64x128 tile -> 704 blocks
    gemm64x128_silu<<<dim3(44, 16), tb, 0, stream>>>(h_bf, w13T, u_bf, 1024);
    // ffn-out partials (split-K=2) -> om2P planes 0,1
    gemm64_sk<<<dim3(16, 16, 2), tb, 0, stream>>>(u_bf, w2T, om2P, 1024, 2816, 1408);
    // om2' = rmsnorm(om2a + p0 + p1, memw)
    rmsnorm_cast<<<1024, tb, 0, stream>>>(om2a, memw, om2_bf, om2P, 2, nullptr);
    // mkv = om2' @ [wkm|wvm] with fused rope (K) / transpose (V)
    gemm64_kmvm<<<dim3(32, 16), tb, 0, stream>>>(om2_bf, wkmvmT, cosf, sinf, k_mem, v_memT);
    // memory-half attention + fused merge with x partials
    attn_mem<<<dim3(8, 32), tb, 0, stream>>>(q_x, k_mem, v_memT,
                                             OpartX + ((size_t)t << 20),
                                             mpartX + (size_t)t * 16384,
                                             lpartX + (size_t)t * 16384,
                                             om_bf, outs_bf, t);
  }
  gemm128<<<dim3(8, 64), tb, 0, stream>>>(outs_bf, woT, d_out, flag, 1024, 1024, 2,
                                          nullptr, nullptr, nullptr, nullptr, nullptr);
}